// Round 16
// baseline (267.994 us; speedup 1.0000x reference)
//
#include <hip/hip_runtime.h>
#include <math.h>

#define NSB   512   // edge-chunk blocks for bucket pass
#define BSH   8     // 256 nodes per bucket
#define BKN   256   // nodes per bucket
#define ESMAX 6272  // max edges per chunk (ceil(3.2M/512)=6250)
#define SLOT  10240 // col/col2 region size per bucket (avg fill 8192, +23 sigma)

typedef _Float16 h8  __attribute__((ext_vector_type(8)));
typedef _Float16 h4  __attribute__((ext_vector_type(4)));
typedef _Float16 h2v __attribute__((ext_vector_type(2)));

// 64-lane inclusive scan (no barriers)
__device__ inline int wave_scan_incl(int v) {
    int lane = threadIdx.x & 63;
#pragma unroll
    for (int d = 1; d < 64; d <<= 1) {
        int t = __shfl_up(v, d, 64);
        if (lane >= d) v += t;
    }
    return v;
}

// ================= bucket pass: LDS counting sort + atomic region allocation =================

__global__ void k_bucket(const int* __restrict__ src, const int* __restrict__ dst,
                         int* __restrict__ gcur, unsigned* __restrict__ col,
                         int e, int nbuck, int es) {
    __shared__ unsigned sorted[ESMAX];
    __shared__ unsigned char sbuck[ESMAX];
    __shared__ int lc[512], lofE[512], lcur[512], soff[512];
    __shared__ int wsum[8];
    int tid = threadIdx.x;
    lc[tid] = 0;
    __syncthreads();
    int lo = blockIdx.x * es;
    int hi = min(lo + es, e);
    for (int i = lo + tid; i < hi; i += 512)
        atomicAdd(&lc[dst[i] >> BSH], 1);
    __syncthreads();
    int c = lc[tid];
    int inc = wave_scan_incl(c);
    int wid = tid >> 6;
    if ((tid & 63) == 63) wsum[wid] = inc;
    __syncthreads();
    int wofs = 0;
#pragma unroll
    for (int w = 0; w < 8; w++) wofs += (w < wid) ? wsum[w] : 0;
    int excl = inc - c + wofs;
    lofE[tid] = excl;
    lcur[tid] = excl;
    if (tid < nbuck && c > 0)
        soff[tid] = tid * SLOT + atomicAdd(&gcur[tid], c);
    __syncthreads();
    for (int i = lo + tid; i < hi; i += 512) {
        int d = dst[i];
        int b = d >> BSH;
        int p = atomicAdd(&lcur[b], 1);
        sorted[p] = ((unsigned)src[i] << BSH) | (unsigned)(d & (BKN - 1));
        sbuck[p] = (unsigned char)(b & 255);
    }
    __syncthreads();
    int cnt_ = hi - lo;
    int split = (nbuck > 256) ? lofE[256] : 0x7fffffff;
    for (int i = tid; i < cnt_; i += 512) {
        int b = sbuck[i] | ((i >= split) ? 256 : 0);
        col[soff[b] + (i - lofE[b])] = sorted[i];
    }
}

// ================= per-bucket counting sort -> CSR (col2, rs, re) + dis =================

__global__ void k_sort(const unsigned* __restrict__ col, const int* __restrict__ gcur,
                       int* __restrict__ col2, int* __restrict__ rs,
                       int* __restrict__ re, float* __restrict__ dis,
                       int n, int nbuck) {
    __shared__ int cnt[BKN];
    __shared__ int cur[BKN];
    __shared__ int wsum[4];
    int tid = threadIdx.x;
    int b = blockIdx.x;
    int lo = b * SLOT;
    int hi = lo + gcur[b];
    if (tid < BKN) cnt[tid] = 0;
    __syncthreads();
    for (int i = lo + tid; i < hi; i += 512)
        atomicAdd(&cnt[col[i] & (BKN - 1u)], 1);
    __syncthreads();
    int c = (tid < BKN) ? cnt[tid] : 0;
    int inc = wave_scan_incl(c);
    int wid = tid >> 6;
    if (tid < BKN && (tid & 63) == 63) wsum[wid] = inc;
    __syncthreads();
    if (tid < BKN) {
        int wofs = 0;
#pragma unroll
        for (int w = 0; w < 4; w++) wofs += (w < wid) ? wsum[w] : 0;
        int excl = inc - c + wofs;
        cur[tid] = lo + excl;
        int node = (b << BSH) + tid;
        if (node < n) {
            rs[node] = lo + excl;
            re[node] = lo + excl + c;
            dis[node] = rsqrtf((float)(c + 1));
        }
    }
    __syncthreads();
    for (int i = lo + tid; i < hi; i += 512) {
        unsigned v = col[i];
        int pos = atomicAdd(&cur[v & (BKN - 1u)], 1);
        col2[pos] = (int)(v >> BSH);
    }
}

// ================= layer-1 linear: hs[n,16] = (x @ W1) * dis, fp16 out =================

__global__ __launch_bounds__(512) void k_linear1s(
        const float* __restrict__ x, const float* __restrict__ W,
        const float* __restrict__ dis, _Float16* __restrict__ hs, int n) {
    __shared__ float sW[2048];
    int tid = threadIdx.x;
    for (int i = tid; i < 2048; i += 512) sW[i] = W[i];
    __syncthreads();
    int cg = tid & 3;
    int kg = (tid >> 2) & 7;
    int nl = tid >> 5;
    float wr[16][4];
#pragma unroll
    for (int j = 0; j < 16; j++)
#pragma unroll
        for (int cc = 0; cc < 4; cc++)
            wr[j][cc] = sW[(kg * 16 + j) * 16 + cg * 4 + cc];
    int nodeBase = blockIdx.x * 128 + nl;
    for (int it = 0; it < 8; it++) {
        int node = nodeBase + it * 16;
        float a0 = 0.f, a1 = 0.f, a2 = 0.f, a3 = 0.f;
        if (node < n) {
            const float4* xr = (const float4*)(x + (size_t)node * 128 + kg * 16);
#pragma unroll
            for (int j4 = 0; j4 < 4; j4++) {
                float4 xv = xr[j4];
                float xs0 = xv.x, xs1 = xv.y, xs2 = xv.z, xs3 = xv.w;
                int j = j4 * 4;
                a0 += xs0 * wr[j][0] + xs1 * wr[j+1][0] + xs2 * wr[j+2][0] + xs3 * wr[j+3][0];
                a1 += xs0 * wr[j][1] + xs1 * wr[j+1][1] + xs2 * wr[j+2][1] + xs3 * wr[j+3][1];
                a2 += xs0 * wr[j][2] + xs1 * wr[j+1][2] + xs2 * wr[j+2][2] + xs3 * wr[j+3][2];
                a3 += xs0 * wr[j][3] + xs1 * wr[j+1][3] + xs2 * wr[j+2][3] + xs3 * wr[j+3][3];
            }
        }
#pragma unroll
        for (int m = 4; m <= 16; m <<= 1) {
            a0 += __shfl_xor(a0, m);
            a1 += __shfl_xor(a1, m);
            a2 += __shfl_xor(a2, m);
            a3 += __shfl_xor(a3, m);
        }
        if (kg == 0 && node < n) {
            float d = dis[node];
            h4 o;
            o[0] = (_Float16)(a0 * d);
            o[1] = (_Float16)(a1 * d);
            o[2] = (_Float16)(a2 * d);
            o[3] = (_Float16)(a3 * d);
            *((h4*)(hs + (size_t)node * 16 + cg * 4)) = o;
        }
    }
}

// ================= fused pull + 16x16 linear (8 threads/node) =================
// nt col2 loads (stream, don't thrash L2) + index prefetch pipeline.

__global__ void k_pullA(const _Float16* __restrict__ hs, const int* __restrict__ rs,
                        const int* __restrict__ re, const int* __restrict__ col2,
                        const float* __restrict__ dis, const float* __restrict__ bb,
                        const float* __restrict__ W, _Float16* __restrict__ hsOut, int n) {
    __shared__ float sW[256];
    __shared__ float sb[16];
    if (threadIdx.x < 256) sW[threadIdx.x] = W[threadIdx.x];
    if (threadIdx.x < 16) sb[threadIdx.x] = bb[threadIdx.x];
    __syncthreads();
    long long t = (long long)blockIdx.x * blockDim.x + threadIdx.x;
    int node = (int)(t >> 3), sub = (int)(t & 7);
    int q = sub & 1, qt = sub >> 1;
    if (node >= n) return;
    const h8* H = (const h8*)hs;
    float acc[8];
    if (qt == 0) {
        h8 self = H[(size_t)node * 2 + q];
#pragma unroll
        for (int j = 0; j < 8; j++) acc[j] = (float)self[j];
    } else {
#pragma unroll
        for (int j = 0; j < 8; j++) acc[j] = 0.f;
    }
    int b = rs[node], e2 = re[node];
    int i = b + qt;
    int s0 = 0, s1 = 0, s2 = 0, s3 = 0;
    bool have = (i + 12 < e2);
    if (have) {
        s0 = __builtin_nontemporal_load(col2 + i);
        s1 = __builtin_nontemporal_load(col2 + i + 4);
        s2 = __builtin_nontemporal_load(col2 + i + 8);
        s3 = __builtin_nontemporal_load(col2 + i + 12);
    }
    while (have) {
        int ni = i + 16;
        int t0 = 0, t1 = 0, t2 = 0, t3 = 0;
        bool nhave = (ni + 12 < e2);
        if (nhave) {                       // prefetch next indices before gathers
            t0 = __builtin_nontemporal_load(col2 + ni);
            t1 = __builtin_nontemporal_load(col2 + ni + 4);
            t2 = __builtin_nontemporal_load(col2 + ni + 8);
            t3 = __builtin_nontemporal_load(col2 + ni + 12);
        }
        h8 v0 = H[(size_t)s0 * 2 + q];
        h8 v1 = H[(size_t)s1 * 2 + q];
        h8 v2 = H[(size_t)s2 * 2 + q];
        h8 v3 = H[(size_t)s3 * 2 + q];
#pragma unroll
        for (int j = 0; j < 8; j++)
            acc[j] += (float)v0[j] + (float)v1[j] + (float)v2[j] + (float)v3[j];
        s0 = t0; s1 = t1; s2 = t2; s3 = t3;
        i = ni; have = nhave;
    }
    for (; i < e2; i += 4) {
        h8 v = H[(size_t)__builtin_nontemporal_load(col2 + i) * 2 + q];
#pragma unroll
        for (int j = 0; j < 8; j++) acc[j] += (float)v[j];
    }
#pragma unroll
    for (int j = 0; j < 8; j++) {
        acc[j] += __shfl_xor(acc[j], 2);
        acc[j] += __shfl_xor(acc[j], 4);
    }
    float d = dis[node];
    float va[16];
#pragma unroll
    for (int j = 0; j < 8; j++) {
        int k = q * 8 + j;
        float v = acc[j] * d + sb[k];
        v = v > 0.f ? v : 0.f;
        float other = __shfl_xor(v, 1);
        va[j]     = q ? other : v;
        va[8 + j] = q ? v : other;
    }
    if (qt == 0) {
        h8 o;
#pragma unroll
        for (int j = 0; j < 8; j++) {
            int c = q * 8 + j;
            float s = 0.f;
#pragma unroll
            for (int k = 0; k < 16; k++) s += va[k] * sW[k * 16 + c];
            o[j] = (_Float16)(s * d);
        }
        ((h8*)hsOut)[(size_t)node * 2 + q] = o;
    }
}

// ================= fused pull + 16x2 linear (8 threads/node) =================

__global__ void k_pullB(const _Float16* __restrict__ hs, const int* __restrict__ rs,
                        const int* __restrict__ re, const int* __restrict__ col2,
                        const float* __restrict__ dis, const float* __restrict__ bb,
                        const float* __restrict__ W, _Float16* __restrict__ hs2, int n) {
    __shared__ float sW[32];
    __shared__ float sb[16];
    if (threadIdx.x < 32) sW[threadIdx.x] = W[threadIdx.x];
    if (threadIdx.x < 16) sb[threadIdx.x] = bb[threadIdx.x];
    __syncthreads();
    long long t = (long long)blockIdx.x * blockDim.x + threadIdx.x;
    int node = (int)(t >> 3), sub = (int)(t & 7);
    int q = sub & 1, qt = sub >> 1;
    if (node >= n) return;
    const h8* H = (const h8*)hs;
    float acc[8];
    if (qt == 0) {
        h8 self = H[(size_t)node * 2 + q];
#pragma unroll
        for (int j = 0; j < 8; j++) acc[j] = (float)self[j];
    } else {
#pragma unroll
        for (int j = 0; j < 8; j++) acc[j] = 0.f;
    }
    int b = rs[node], e2 = re[node];
    int i = b + qt;
    int s0 = 0, s1 = 0, s2 = 0, s3 = 0;
    bool have = (i + 12 < e2);
    if (have) {
        s0 = __builtin_nontemporal_load(col2 + i);
        s1 = __builtin_nontemporal_load(col2 + i + 4);
        s2 = __builtin_nontemporal_load(col2 + i + 8);
        s3 = __builtin_nontemporal_load(col2 + i + 12);
    }
    while (have) {
        int ni = i + 16;
        int t0 = 0, t1 = 0, t2 = 0, t3 = 0;
        bool nhave = (ni + 12 < e2);
        if (nhave) {
            t0 = __builtin_nontemporal_load(col2 + ni);
            t1 = __builtin_nontemporal_load(col2 + ni + 4);
            t2 = __builtin_nontemporal_load(col2 + ni + 8);
            t3 = __builtin_nontemporal_load(col2 + ni + 12);
        }
        h8 v0 = H[(size_t)s0 * 2 + q];
        h8 v1 = H[(size_t)s1 * 2 + q];
        h8 v2 = H[(size_t)s2 * 2 + q];
        h8 v3 = H[(size_t)s3 * 2 + q];
#pragma unroll
        for (int j = 0; j < 8; j++)
            acc[j] += (float)v0[j] + (float)v1[j] + (float)v2[j] + (float)v3[j];
        s0 = t0; s1 = t1; s2 = t2; s3 = t3;
        i = ni; have = nhave;
    }
    for (; i < e2; i += 4) {
        h8 v = H[(size_t)__builtin_nontemporal_load(col2 + i) * 2 + q];
#pragma unroll
        for (int j = 0; j < 8; j++) acc[j] += (float)v[j];
    }
#pragma unroll
    for (int j = 0; j < 8; j++) {
        acc[j] += __shfl_xor(acc[j], 2);
        acc[j] += __shfl_xor(acc[j], 4);
    }
    float d = dis[node];
    float p0 = 0.f, p1 = 0.f;
#pragma unroll
    for (int j = 0; j < 8; j++) {
        int k = q * 8 + j;
        float v = acc[j] * d + sb[k];
        v = v > 0.f ? v : 0.f;
        p0 += v * sW[k * 2 + 0];
        p1 += v * sW[k * 2 + 1];
    }
    p0 += __shfl_xor(p0, 1);
    p1 += __shfl_xor(p1, 1);
    if (sub == 0) {
        h2v o;
        o[0] = (_Float16)(p0 * d);
        o[1] = (_Float16)(p1 * d);
        ((h2v*)hs2)[node] = o;
    }
}

// ================= final pull + bias + log_softmax (4 threads/node) =================

__global__ void k_pull2lsm(const _Float16* __restrict__ hs2, const int* __restrict__ rs,
                           const int* __restrict__ re, const int* __restrict__ col2,
                           const float* __restrict__ dis, const float* __restrict__ b3,
                           float* __restrict__ out, int n) {
    long long t = (long long)blockIdx.x * blockDim.x + threadIdx.x;
    int node = (int)(t >> 2), qt = (int)(t & 3);
    if (node >= n) return;
    const h2v* H = (const h2v*)hs2;
    float a0 = 0.f, a1 = 0.f;
    if (qt == 0) {
        h2v self = H[node];
        a0 = (float)self[0]; a1 = (float)self[1];
    }
    int b = rs[node], e2 = re[node];
    int i = b + qt;
    int s0 = 0, s1 = 0, s2 = 0, s3 = 0;
    bool have = (i + 12 < e2);
    if (have) {
        s0 = __builtin_nontemporal_load(col2 + i);
        s1 = __builtin_nontemporal_load(col2 + i + 4);
        s2 = __builtin_nontemporal_load(col2 + i + 8);
        s3 = __builtin_nontemporal_load(col2 + i + 12);
    }
    while (have) {
        int ni = i + 16;
        int t0 = 0, t1 = 0, t2 = 0, t3 = 0;
        bool nhave = (ni + 12 < e2);
        if (nhave) {
            t0 = __builtin_nontemporal_load(col2 + ni);
            t1 = __builtin_nontemporal_load(col2 + ni + 4);
            t2 = __builtin_nontemporal_load(col2 + ni + 8);
            t3 = __builtin_nontemporal_load(col2 + ni + 12);
        }
        h2v v0 = H[s0];
        h2v v1 = H[s1];
        h2v v2 = H[s2];
        h2v v3 = H[s3];
        a0 += (float)v0[0] + (float)v1[0] + (float)v2[0] + (float)v3[0];
        a1 += (float)v0[1] + (float)v1[1] + (float)v2[1] + (float)v3[1];
        s0 = t0; s1 = t1; s2 = t2; s3 = t3;
        i = ni; have = nhave;
    }
    for (; i < e2; i += 4) {
        h2v v = H[__builtin_nontemporal_load(col2 + i)];
        a0 += (float)v[0];
        a1 += (float)v[1];
    }
    a0 += __shfl_xor(a0, 1); a0 += __shfl_xor(a0, 2);
    a1 += __shfl_xor(a1, 1); a1 += __shfl_xor(a1, 2);
    if (qt == 0) {
        float d = dis[node];
        float z0 = a0 * d + b3[0];
        float z1 = a1 * d + b3[1];
        float m = fmaxf(z0, z1);
        float l = m + logf(expf(z0 - m) + expf(z1 - m));
        float2 o = {z0 - l, z1 - l};
        ((float2*)out)[node] = o;
    }
}

// ================= launch =================

extern "C" void kernel_launch(void* const* d_in, const int* in_sizes, int n_in,
                              void* d_out, int out_size, void* d_ws, size_t ws_size,
                              hipStream_t stream) {
    const float* x  = (const float*)d_in[0];
    const int*   ei = (const int*)d_in[1];
    const float* W1 = (const float*)d_in[2];
    const float* b1 = (const float*)d_in[3];
    const float* W2 = (const float*)d_in[4];
    const float* b2 = (const float*)d_in[5];
    const float* W3 = (const float*)d_in[6];
    const float* b3 = (const float*)d_in[7];
    float* out = (float*)d_out;

    const int N = in_sizes[0] / 128;
    const int E = in_sizes[1] / 2;
    const int* src = ei;
    const int* dst = ei + E;

    const int NBUCK = (N + BKN - 1) >> BSH;      // 391 for N=100000 (<= 512)
    const int ES = (E + NSB - 1) / NSB;          // 6250 (<= ESMAX)

    char* ws = (char*)d_ws;
    size_t off = 0;
    auto alloc = [&](size_t bytes) {
        void* p = ws + off;
        off += (bytes + 255) & ~(size_t)255;
        return p;
    };
    int*       gcur = (int*)alloc((size_t)NBUCK * sizeof(int));
    unsigned*  col  = (unsigned*)alloc((size_t)NBUCK * SLOT * sizeof(unsigned));
    int*       col2 = (int*)alloc((size_t)NBUCK * SLOT * sizeof(int));
    int*       rs   = (int*)alloc((size_t)N * sizeof(int));
    int*       re   = (int*)alloc((size_t)N * sizeof(int));
    float*     dis  = (float*)alloc((size_t)N * sizeof(float));
    _Float16*  hsA  = (_Float16*)alloc((size_t)N * 16 * sizeof(_Float16));
    _Float16*  hsB  = (_Float16*)alloc((size_t)N * 16 * sizeof(_Float16));
    _Float16*  hs2  = (_Float16*)alloc((size_t)N * 2 * sizeof(_Float16));

    const int B = 256;
    auto g = [&](long long work) { return (int)((work + B - 1) / B); };

    // ---- CSR build ----
    hipMemsetAsync(gcur, 0, (size_t)NBUCK * sizeof(int), stream);
    k_bucket<<<NSB, 512, 0, stream>>>(src, dst, gcur, col, E, NBUCK, ES);
    k_sort<<<NBUCK, 512, 0, stream>>>(col, gcur, col2, rs, re, dis, N, NBUCK);

    // ---- layer 1 linear ----
    k_linear1s<<<(N + 127) / 128, 512, 0, stream>>>(x, W1, dis, hsA, N);

    // ---- agg1 + layer2 linear (fused, 8 threads/node) ----
    k_pullA<<<g((long long)N * 8), B, 0, stream>>>(hsA, rs, re, col2, dis, b1, W2, hsB, N);

    // ---- agg2 + layer3 linear (fused, 8 threads/node) ----
    k_pullB<<<g((long long)N * 8), B, 0, stream>>>(hsB, rs, re, col2, dis, b2, W3, hs2, N);

    // ---- agg3 + bias + log_softmax (fused, 4 threads/node) ----
    k_pull2lsm<<<g((long long)N * 4), B, 0, stream>>>(hs2, rs, re, col2, dis, b3, out, N);
}

// Round 17
// 243.647 us; speedup vs baseline: 1.0999x; 1.0999x over previous
//
#include <hip/hip_runtime.h>
#include <math.h>

#define NSB   512   // edge-chunk blocks for bucket pass
#define BSH   8     // 256 nodes per bucket
#define BKN   256   // nodes per bucket
#define ESMAX 6272  // max edges per chunk (ceil(3.2M/512)=6250)
#define SLOT  10240 // col/col2 region size per bucket (avg fill 8192, +23 sigma)

typedef _Float16 h8  __attribute__((ext_vector_type(8)));
typedef _Float16 h4  __attribute__((ext_vector_type(4)));
typedef _Float16 h2v __attribute__((ext_vector_type(2)));

// 64-lane inclusive scan (no barriers)
__device__ inline int wave_scan_incl(int v) {
    int lane = threadIdx.x & 63;
#pragma unroll
    for (int d = 1; d < 64; d <<= 1) {
        int t = __shfl_up(v, d, 64);
        if (lane >= d) v += t;
    }
    return v;
}

// ================= bucket pass: LDS counting sort + atomic region allocation =================

__global__ void k_bucket(const int* __restrict__ src, const int* __restrict__ dst,
                         int* __restrict__ gcur, unsigned* __restrict__ col,
                         int e, int nbuck, int es) {
    __shared__ unsigned sorted[ESMAX];
    __shared__ unsigned char sbuck[ESMAX];
    __shared__ int lc[512], lofE[512], lcur[512], soff[512];
    __shared__ int wsum[8];
    int tid = threadIdx.x;
    lc[tid] = 0;
    __syncthreads();
    int lo = blockIdx.x * es;
    int hi = min(lo + es, e);
    for (int i = lo + tid; i < hi; i += 512)
        atomicAdd(&lc[dst[i] >> BSH], 1);
    __syncthreads();
    int c = lc[tid];
    int inc = wave_scan_incl(c);
    int wid = tid >> 6;
    if ((tid & 63) == 63) wsum[wid] = inc;
    __syncthreads();
    int wofs = 0;
#pragma unroll
    for (int w = 0; w < 8; w++) wofs += (w < wid) ? wsum[w] : 0;
    int excl = inc - c + wofs;
    lofE[tid] = excl;
    lcur[tid] = excl;
    if (tid < nbuck && c > 0)
        soff[tid] = tid * SLOT + atomicAdd(&gcur[tid], c);
    __syncthreads();
    for (int i = lo + tid; i < hi; i += 512) {
        int d = dst[i];
        int b = d >> BSH;
        int p = atomicAdd(&lcur[b], 1);
        sorted[p] = ((unsigned)src[i] << BSH) | (unsigned)(d & (BKN - 1));
        sbuck[p] = (unsigned char)(b & 255);
    }
    __syncthreads();
    int cnt_ = hi - lo;
    int split = (nbuck > 256) ? lofE[256] : 0x7fffffff;
    for (int i = tid; i < cnt_; i += 512) {
        int b = sbuck[i] | ((i >= split) ? 256 : 0);
        col[soff[b] + (i - lofE[b])] = sorted[i];
    }
}

// ================= per-bucket counting sort -> CSR (col2, rs, re) + dis =================

__global__ void k_sort(const unsigned* __restrict__ col, const int* __restrict__ gcur,
                       int* __restrict__ col2, int* __restrict__ rs,
                       int* __restrict__ re, float* __restrict__ dis,
                       int n, int nbuck) {
    __shared__ int cnt[BKN];
    __shared__ int cur[BKN];
    __shared__ int wsum[4];
    int tid = threadIdx.x;
    int b = blockIdx.x;
    int lo = b * SLOT;
    int hi = lo + gcur[b];
    if (tid < BKN) cnt[tid] = 0;
    __syncthreads();
    for (int i = lo + tid; i < hi; i += 512)
        atomicAdd(&cnt[col[i] & (BKN - 1u)], 1);
    __syncthreads();
    int c = (tid < BKN) ? cnt[tid] : 0;
    int inc = wave_scan_incl(c);
    int wid = tid >> 6;
    if (tid < BKN && (tid & 63) == 63) wsum[wid] = inc;
    __syncthreads();
    if (tid < BKN) {
        int wofs = 0;
#pragma unroll
        for (int w = 0; w < 4; w++) wofs += (w < wid) ? wsum[w] : 0;
        int excl = inc - c + wofs;
        cur[tid] = lo + excl;
        int node = (b << BSH) + tid;
        if (node < n) {
            rs[node] = lo + excl;
            re[node] = lo + excl + c;
            dis[node] = rsqrtf((float)(c + 1));
        }
    }
    __syncthreads();
    for (int i = lo + tid; i < hi; i += 512) {
        unsigned v = col[i];
        int pos = atomicAdd(&cur[v & (BKN - 1u)], 1);
        col2[pos] = (int)(v >> BSH);
    }
}

// ================= layer-1 linear: hs[n,16] = (x @ W1) * dis, fp16 out =================

__global__ __launch_bounds__(512) void k_linear1s(
        const float* __restrict__ x, const float* __restrict__ W,
        const float* __restrict__ dis, _Float16* __restrict__ hs, int n) {
    __shared__ float sW[2048];
    int tid = threadIdx.x;
    for (int i = tid; i < 2048; i += 512) sW[i] = W[i];
    __syncthreads();
    int cg = tid & 3;
    int kg = (tid >> 2) & 7;
    int nl = tid >> 5;
    float wr[16][4];
#pragma unroll
    for (int j = 0; j < 16; j++)
#pragma unroll
        for (int cc = 0; cc < 4; cc++)
            wr[j][cc] = sW[(kg * 16 + j) * 16 + cg * 4 + cc];
    int nodeBase = blockIdx.x * 128 + nl;
    for (int it = 0; it < 8; it++) {
        int node = nodeBase + it * 16;
        float a0 = 0.f, a1 = 0.f, a2 = 0.f, a3 = 0.f;
        if (node < n) {
            const float4* xr = (const float4*)(x + (size_t)node * 128 + kg * 16);
#pragma unroll
            for (int j4 = 0; j4 < 4; j4++) {
                float4 xv = xr[j4];
                float xs0 = xv.x, xs1 = xv.y, xs2 = xv.z, xs3 = xv.w;
                int j = j4 * 4;
                a0 += xs0 * wr[j][0] + xs1 * wr[j+1][0] + xs2 * wr[j+2][0] + xs3 * wr[j+3][0];
                a1 += xs0 * wr[j][1] + xs1 * wr[j+1][1] + xs2 * wr[j+2][1] + xs3 * wr[j+3][1];
                a2 += xs0 * wr[j][2] + xs1 * wr[j+1][2] + xs2 * wr[j+2][2] + xs3 * wr[j+3][2];
                a3 += xs0 * wr[j][3] + xs1 * wr[j+1][3] + xs2 * wr[j+2][3] + xs3 * wr[j+3][3];
            }
        }
#pragma unroll
        for (int m = 4; m <= 16; m <<= 1) {
            a0 += __shfl_xor(a0, m);
            a1 += __shfl_xor(a1, m);
            a2 += __shfl_xor(a2, m);
            a3 += __shfl_xor(a3, m);
        }
        if (kg == 0 && node < n) {
            float d = dis[node];
            h4 o;
            o[0] = (_Float16)(a0 * d);
            o[1] = (_Float16)(a1 * d);
            o[2] = (_Float16)(a2 * d);
            o[3] = (_Float16)(a3 * d);
            *((h4*)(hs + (size_t)node * 16 + cg * 4)) = o;
        }
    }
}

// ================= fused pull + 16x16 linear (8 threads/node) =================
// sub = t&7: q = sub&1 (channel half), qt = sub>>1 (edge lane 0..3).
// Edges interleaved stride-4 (coalesced col2); reduce via shfl_xor 2,4; exchange
// activations via shfl_xor 1.

__global__ void k_pullA(const _Float16* __restrict__ hs, const int* __restrict__ rs,
                        const int* __restrict__ re, const int* __restrict__ col2,
                        const float* __restrict__ dis, const float* __restrict__ bb,
                        const float* __restrict__ W, _Float16* __restrict__ hsOut, int n) {
    __shared__ float sW[256];
    __shared__ float sb[16];
    if (threadIdx.x < 256) sW[threadIdx.x] = W[threadIdx.x];
    if (threadIdx.x < 16) sb[threadIdx.x] = bb[threadIdx.x];
    __syncthreads();
    long long t = (long long)blockIdx.x * blockDim.x + threadIdx.x;
    int node = (int)(t >> 3), sub = (int)(t & 7);
    int q = sub & 1, qt = sub >> 1;
    if (node >= n) return;
    const h8* H = (const h8*)hs;
    float acc[8];
    if (qt == 0) {
        h8 self = H[(size_t)node * 2 + q];
#pragma unroll
        for (int j = 0; j < 8; j++) acc[j] = (float)self[j];
    } else {
#pragma unroll
        for (int j = 0; j < 8; j++) acc[j] = 0.f;
    }
    int b = rs[node], e2 = re[node];
    int i = b + qt;
    for (; i + 12 < e2; i += 16) {
        int s0 = col2[i], s1 = col2[i + 4], s2 = col2[i + 8], s3 = col2[i + 12];
        h8 v0 = H[(size_t)s0 * 2 + q];
        h8 v1 = H[(size_t)s1 * 2 + q];
        h8 v2 = H[(size_t)s2 * 2 + q];
        h8 v3 = H[(size_t)s3 * 2 + q];
#pragma unroll
        for (int j = 0; j < 8; j++)
            acc[j] += (float)v0[j] + (float)v1[j] + (float)v2[j] + (float)v3[j];
    }
    for (; i < e2; i += 4) {
        h8 v = H[(size_t)col2[i] * 2 + q];
#pragma unroll
        for (int j = 0; j < 8; j++) acc[j] += (float)v[j];
    }
#pragma unroll
    for (int j = 0; j < 8; j++) {
        acc[j] += __shfl_xor(acc[j], 2);
        acc[j] += __shfl_xor(acc[j], 4);
    }
    float d = dis[node];
    float va[16];
#pragma unroll
    for (int j = 0; j < 8; j++) {
        int k = q * 8 + j;
        float v = acc[j] * d + sb[k];
        v = v > 0.f ? v : 0.f;
        float other = __shfl_xor(v, 1);
        va[j]     = q ? other : v;
        va[8 + j] = q ? v : other;
    }
    if (qt == 0) {
        h8 o;
#pragma unroll
        for (int j = 0; j < 8; j++) {
            int c = q * 8 + j;
            float s = 0.f;
#pragma unroll
            for (int k = 0; k < 16; k++) s += va[k] * sW[k * 16 + c];
            o[j] = (_Float16)(s * d);
        }
        ((h8*)hsOut)[(size_t)node * 2 + q] = o;
    }
}

// ================= fused pull + 16x2 linear (8 threads/node) =================

__global__ void k_pullB(const _Float16* __restrict__ hs, const int* __restrict__ rs,
                        const int* __restrict__ re, const int* __restrict__ col2,
                        const float* __restrict__ dis, const float* __restrict__ bb,
                        const float* __restrict__ W, _Float16* __restrict__ hs2, int n) {
    __shared__ float sW[32];
    __shared__ float sb[16];
    if (threadIdx.x < 32) sW[threadIdx.x] = W[threadIdx.x];
    if (threadIdx.x < 16) sb[threadIdx.x] = bb[threadIdx.x];
    __syncthreads();
    long long t = (long long)blockIdx.x * blockDim.x + threadIdx.x;
    int node = (int)(t >> 3), sub = (int)(t & 7);
    int q = sub & 1, qt = sub >> 1;
    if (node >= n) return;
    const h8* H = (const h8*)hs;
    float acc[8];
    if (qt == 0) {
        h8 self = H[(size_t)node * 2 + q];
#pragma unroll
        for (int j = 0; j < 8; j++) acc[j] = (float)self[j];
    } else {
#pragma unroll
        for (int j = 0; j < 8; j++) acc[j] = 0.f;
    }
    int b = rs[node], e2 = re[node];
    int i = b + qt;
    for (; i + 12 < e2; i += 16) {
        int s0 = col2[i], s1 = col2[i + 4], s2 = col2[i + 8], s3 = col2[i + 12];
        h8 v0 = H[(size_t)s0 * 2 + q];
        h8 v1 = H[(size_t)s1 * 2 + q];
        h8 v2 = H[(size_t)s2 * 2 + q];
        h8 v3 = H[(size_t)s3 * 2 + q];
#pragma unroll
        for (int j = 0; j < 8; j++)
            acc[j] += (float)v0[j] + (float)v1[j] + (float)v2[j] + (float)v3[j];
    }
    for (; i < e2; i += 4) {
        h8 v = H[(size_t)col2[i] * 2 + q];
#pragma unroll
        for (int j = 0; j < 8; j++) acc[j] += (float)v[j];
    }
#pragma unroll
    for (int j = 0; j < 8; j++) {
        acc[j] += __shfl_xor(acc[j], 2);
        acc[j] += __shfl_xor(acc[j], 4);
    }
    float d = dis[node];
    float p0 = 0.f, p1 = 0.f;
#pragma unroll
    for (int j = 0; j < 8; j++) {
        int k = q * 8 + j;
        float v = acc[j] * d + sb[k];
        v = v > 0.f ? v : 0.f;
        p0 += v * sW[k * 2 + 0];
        p1 += v * sW[k * 2 + 1];
    }
    p0 += __shfl_xor(p0, 1);
    p1 += __shfl_xor(p1, 1);
    if (sub == 0) {
        h2v o;
        o[0] = (_Float16)(p0 * d);
        o[1] = (_Float16)(p1 * d);
        ((h2v*)hs2)[node] = o;
    }
}

// ================= final pull + bias + log_softmax (4 threads/node) =================

__global__ void k_pull2lsm(const _Float16* __restrict__ hs2, const int* __restrict__ rs,
                           const int* __restrict__ re, const int* __restrict__ col2,
                           const float* __restrict__ dis, const float* __restrict__ b3,
                           float* __restrict__ out, int n) {
    long long t = (long long)blockIdx.x * blockDim.x + threadIdx.x;
    int node = (int)(t >> 2), qt = (int)(t & 3);
    if (node >= n) return;
    const h2v* H = (const h2v*)hs2;
    float a0 = 0.f, a1 = 0.f;
    if (qt == 0) {
        h2v self = H[node];
        a0 = (float)self[0]; a1 = (float)self[1];
    }
    int b = rs[node], e2 = re[node];
    int i = b + qt;
    for (; i + 12 < e2; i += 16) {
        h2v v0 = H[col2[i]];
        h2v v1 = H[col2[i + 4]];
        h2v v2 = H[col2[i + 8]];
        h2v v3 = H[col2[i + 12]];
        a0 += (float)v0[0] + (float)v1[0] + (float)v2[0] + (float)v3[0];
        a1 += (float)v0[1] + (float)v1[1] + (float)v2[1] + (float)v3[1];
    }
    for (; i < e2; i += 4) {
        h2v v = H[col2[i]];
        a0 += (float)v[0];
        a1 += (float)v[1];
    }
    a0 += __shfl_xor(a0, 1); a0 += __shfl_xor(a0, 2);
    a1 += __shfl_xor(a1, 1); a1 += __shfl_xor(a1, 2);
    if (qt == 0) {
        float d = dis[node];
        float z0 = a0 * d + b3[0];
        float z1 = a1 * d + b3[1];
        float m = fmaxf(z0, z1);
        float l = m + logf(expf(z0 - m) + expf(z1 - m));
        float2 o = {z0 - l, z1 - l};
        ((float2*)out)[node] = o;
    }
}

// ================= launch =================

extern "C" void kernel_launch(void* const* d_in, const int* in_sizes, int n_in,
                              void* d_out, int out_size, void* d_ws, size_t ws_size,
                              hipStream_t stream) {
    const float* x  = (const float*)d_in[0];
    const int*   ei = (const int*)d_in[1];
    const float* W1 = (const float*)d_in[2];
    const float* b1 = (const float*)d_in[3];
    const float* W2 = (const float*)d_in[4];
    const float* b2 = (const float*)d_in[5];
    const float* W3 = (const float*)d_in[6];
    const float* b3 = (const float*)d_in[7];
    float* out = (float*)d_out;

    const int N = in_sizes[0] / 128;
    const int E = in_sizes[1] / 2;
    const int* src = ei;
    const int* dst = ei + E;

    const int NBUCK = (N + BKN - 1) >> BSH;      // 391 for N=100000 (<= 512)
    const int ES = (E + NSB - 1) / NSB;          // 6250 (<= ESMAX)

    char* ws = (char*)d_ws;
    size_t off = 0;
    auto alloc = [&](size_t bytes) {
        void* p = ws + off;
        off += (bytes + 255) & ~(size_t)255;
        return p;
    };
    int*       gcur = (int*)alloc((size_t)NBUCK * sizeof(int));
    unsigned*  col  = (unsigned*)alloc((size_t)NBUCK * SLOT * sizeof(unsigned));
    int*       col2 = (int*)alloc((size_t)NBUCK * SLOT * sizeof(int));
    int*       rs   = (int*)alloc((size_t)N * sizeof(int));
    int*       re   = (int*)alloc((size_t)N * sizeof(int));
    float*     dis  = (float*)alloc((size_t)N * sizeof(float));
    _Float16*  hsA  = (_Float16*)alloc((size_t)N * 16 * sizeof(_Float16));
    _Float16*  hsB  = (_Float16*)alloc((size_t)N * 16 * sizeof(_Float16));
    _Float16*  hs2  = (_Float16*)alloc((size_t)N * 2 * sizeof(_Float16));

    const int B = 256;
    auto g = [&](long long work) { return (int)((work + B - 1) / B); };

    // ---- CSR build: zero region cursors, bucket w/ atomic allocation, sort ----
    hipMemsetAsync(gcur, 0, (size_t)NBUCK * sizeof(int), stream);
    k_bucket<<<NSB, 512, 0, stream>>>(src, dst, gcur, col, E, NBUCK, ES);
    k_sort<<<NBUCK, 512, 0, stream>>>(col, gcur, col2, rs, re, dis, N, NBUCK);

    // ---- layer 1 linear ----
    k_linear1s<<<(N + 127) / 128, 512, 0, stream>>>(x, W1, dis, hsA, N);

    // ---- agg1 + layer2 linear (fused, 8 threads/node) ----
    k_pullA<<<g((long long)N * 8), B, 0, stream>>>(hsA, rs, re, col2, dis, b1, W2, hsB, N);

    // ---- agg2 + layer3 linear (fused, 8 threads/node) ----
    k_pullB<<<g((long long)N * 8), B, 0, stream>>>(hsB, rs, re, col2, dis, b2, W3, hs2, N);

    // ---- agg3 + bias + log_softmax (fused, 4 threads/node) ----
    k_pull2lsm<<<g((long long)N * 4), B, 0, stream>>>(hs2, rs, re, col2, dis, b3, out, N);
}